// Round 3
// baseline (114.437 us; speedup 1.0000x reference)
//
#include <hip/hip_runtime.h>
#include <hip/hip_bf16.h>

typedef __bf16 bf16;
typedef __attribute__((ext_vector_type(4))) __bf16 bf16x4;
typedef __attribute__((ext_vector_type(8))) __bf16 bf16x8;
typedef __attribute__((ext_vector_type(4))) float f32x4;

#define GLD_LDS16(g, l)                                              \
  __builtin_amdgcn_global_load_lds(                                  \
      (const __attribute__((address_space(1))) void*)(g),            \
      (__attribute__((address_space(3))) void*)(l), 16, 0, 0)

// ---------------- cast f32 -> bf16, vectorized ----------------
__global__ void cast_bf16_kernel(const float* __restrict__ in,
                                 bf16* __restrict__ out, int n4) {
  int i = blockIdx.x * blockDim.x + threadIdx.x;
  if (i >= n4) return;
  float4 v = reinterpret_cast<const float4*>(in)[i];
  bf16x4 o;
  o[0] = (bf16)v.x; o[1] = (bf16)v.y; o[2] = (bf16)v.z; o[3] = (bf16)v.w;
  reinterpret_cast<bf16x4*>(out)[i] = o;
}

// ---------------- transpose + cast W (K,N) -> Wt (N,K) bf16 ----------------
__global__ void transpose_cast_kernel(const float* __restrict__ Wq,
                                      const float* __restrict__ Wk,
                                      const float* __restrict__ Wv,
                                      bf16* __restrict__ Wt) {
  __shared__ float tile[32][33];  // +1 pad breaks bank conflicts
  const int z = blockIdx.z;
  const float* W = (z == 0) ? Wq : ((z == 1) ? Wk : Wv);
  bf16* out = Wt + (size_t)z * 1024 * 1024;
  const int k0 = blockIdx.x * 32, n0 = blockIdx.y * 32;
  const int t = threadIdx.x;
  const int r = t >> 3, c = (t & 7) * 4;  // 32 rows x 32 cols via 256 thr x float4
  float4 v = *reinterpret_cast<const float4*>(&W[(size_t)(k0 + r) * 1024 + n0 + c]);
  tile[r][c + 0] = v.x; tile[r][c + 1] = v.y;
  tile[r][c + 2] = v.z; tile[r][c + 3] = v.w;
  __syncthreads();
  bf16x4 o;
  o[0] = (bf16)tile[c + 0][r]; o[1] = (bf16)tile[c + 1][r];
  o[2] = (bf16)tile[c + 2][r]; o[3] = (bf16)tile[c + 3][r];
  *reinterpret_cast<bf16x4*>(&out[(size_t)(n0 + r) * 1024 + k0 + c]) = o;
}

// ---------------- QKV GEMM: C = x @ W + b, m97 structure ----------------
// x: (8192,1024) bf16 row-major.  Wt: (N=1024, K=1024) bf16 (pre-transposed).
// Tile 128x128, BK=32, 4 waves each computing 64x64 (4x4 frags of 16x16x32).
__global__ void qkv_gemm_kernel(const bf16* __restrict__ xb,
                                const bf16* __restrict__ Wt,
                                const float* __restrict__ bq,
                                const float* __restrict__ bk,
                                const float* __restrict__ bv,
                                bf16* __restrict__ QKV) {
  __shared__ bf16 ldsA[128 * 32];  // 8 KB, linear: row-major [128][32]
  __shared__ bf16 ldsB[128 * 32];  // 8 KB
  const int z = blockIdx.z;
  const bf16* wt = Wt + (size_t)z * 1024 * 1024;
  const float* bias = (z == 0) ? bq : ((z == 1) ? bk : bv);
  bf16* out = QKV + (size_t)z * 8192 * 1024;
  const int n0 = blockIdx.x * 128;
  const int m0 = blockIdx.y * 128;
  const int t = threadIdx.x;
  const int lane = t & 63, wid = t >> 6;
  const int wr = wid >> 1, wc = wid & 1;      // wave -> 64x64 subtile
  const int l15 = lane & 15, kg = lane >> 4;  // MFMA fragment indices

  f32x4 acc[4][4];
#pragma unroll
  for (int i = 0; i < 4; ++i)
#pragma unroll
    for (int j = 0; j < 4; ++j) {
      f32x4 zz = {0.f, 0.f, 0.f, 0.f};
      acc[i][j] = zz;
    }

  // staging geometry: per gload_lds instruction i, thread t covers
  // row = i*64 + t/4, col = (t%4)*8; LDS byte offset = i*4096 + t*16 (linear)
  const int rS = t >> 2;
  const int cS = (t & 3) * 8;

  for (int k0 = 0; k0 < 1024; k0 += 32) {
    if (k0) __syncthreads();
#pragma unroll
    for (int i = 0; i < 2; ++i) {
      GLD_LDS16(xb + (size_t)(m0 + i * 64 + rS) * 1024 + k0 + cS,
                &ldsA[i * 2048 + t * 8]);
      GLD_LDS16(wt + (size_t)(n0 + i * 64 + rS) * 1024 + k0 + cS,
                &ldsB[i * 2048 + t * 8]);
    }
    __syncthreads();  // drains vmcnt before any wave reads

    bf16x8 af[4], bfr[4];
#pragma unroll
    for (int mi = 0; mi < 4; ++mi)
      af[mi] = *reinterpret_cast<const bf16x8*>(
          &ldsA[(wr * 64 + mi * 16 + l15) * 32 + kg * 8]);
#pragma unroll
    for (int ni = 0; ni < 4; ++ni)
      bfr[ni] = *reinterpret_cast<const bf16x8*>(
          &ldsB[(wc * 64 + ni * 16 + l15) * 32 + kg * 8]);
#pragma unroll
    for (int mi = 0; mi < 4; ++mi)
#pragma unroll
      for (int ni = 0; ni < 4; ++ni)
        acc[mi][ni] = __builtin_amdgcn_mfma_f32_16x16x32_bf16(
            af[mi], bfr[ni], acc[mi][ni], 0, 0, 0);
  }

  // epilogue: C/D layout col = lane&15, row = (lane>>4)*4 + reg  [m89/m91]
  const int rowb = kg * 4;
#pragma unroll
  for (int ni = 0; ni < 4; ++ni) {
    const int col = n0 + wc * 64 + ni * 16 + l15;
    const float bv_ = bias[col];
#pragma unroll
    for (int mi = 0; mi < 4; ++mi) {
      const int row = m0 + wr * 64 + mi * 16 + rowb;
#pragma unroll
      for (int j = 0; j < 4; ++j)
        out[(size_t)(row + j) * 1024 + col] = (bf16)(acc[mi][ni][j] + bv_);
    }
  }
}

// ---------------- local attention, window +-2, one wave per position -------
__global__ void local_attn_kernel(const bf16* __restrict__ QKV,
                                  float* __restrict__ out) {
  const int t = threadIdx.x;
  const int lane = t & 63, wid = t >> 6;
  const int p = blockIdx.x * 4 + wid;  // 0..8191 = b*2048 + s
  const int s = p & 2047;
  const bf16* Q = QKV;
  const bf16* K = QKV + (size_t)8192 * 1024;
  const bf16* V = QKV + (size_t)2 * 8192 * 1024;
  const size_t hoff = (size_t)lane * 16;

  float qf[16];
  {
    const size_t qo = (size_t)p * 1024 + hoff;
    bf16x8 q0 = *reinterpret_cast<const bf16x8*>(&Q[qo]);
    bf16x8 q1 = *reinterpret_cast<const bf16x8*>(&Q[qo + 8]);
#pragma unroll
    for (int j = 0; j < 8; ++j) {
      qf[j] = (float)q0[j];
      qf[8 + j] = (float)q1[j];
    }
  }

  float sc[5];
#pragma unroll
  for (int w = 0; w < 5; ++w) {
    const int sp = s + w - 2;  // wave-uniform branch
    if (sp < 0 || sp >= 2048) {
      sc[w] = -__builtin_inff();
      continue;
    }
    const size_t ko = (size_t)(p + w - 2) * 1024 + hoff;
    bf16x8 k0 = *reinterpret_cast<const bf16x8*>(&K[ko]);
    bf16x8 k1 = *reinterpret_cast<const bf16x8*>(&K[ko + 8]);
    float d = 0.f;
#pragma unroll
    for (int j = 0; j < 8; ++j)
      d += qf[j] * (float)k0[j] + qf[8 + j] * (float)k1[j];
#pragma unroll
    for (int off = 32; off >= 1; off >>= 1) d += __shfl_xor(d, off, 64);
    sc[w] = d * (1.0f / 32.0f);  // /sqrt(1024)
  }

  float m = -__builtin_inff();
#pragma unroll
  for (int w = 0; w < 5; ++w) m = fmaxf(m, sc[w]);
  float e[5], sum = 0.f;
#pragma unroll
  for (int w = 0; w < 5; ++w) {
    e[w] = __expf(sc[w] - m);
    sum += e[w];
  }
  const float inv = 1.0f / sum;

  float of[16];
#pragma unroll
  for (int j = 0; j < 16; ++j) of[j] = 0.f;
#pragma unroll
  for (int w = 0; w < 5; ++w) {
    const int sp = s + w - 2;
    if (sp < 0 || sp >= 2048) continue;  // guard OOB; wave-uniform
    const float pw = e[w] * inv;
    const size_t vo = (size_t)(p + w - 2) * 1024 + hoff;
    bf16x8 v0 = *reinterpret_cast<const bf16x8*>(&V[vo]);
    bf16x8 v1 = *reinterpret_cast<const bf16x8*>(&V[vo + 8]);
#pragma unroll
    for (int j = 0; j < 8; ++j) {
      of[j] += pw * (float)v0[j];
      of[8 + j] += pw * (float)v1[j];
    }
  }

  float* op = out + (size_t)p * 1024 + hoff;
#pragma unroll
  for (int j4 = 0; j4 < 4; ++j4) {
    f32x4 o = {of[4 * j4 + 0], of[4 * j4 + 1], of[4 * j4 + 2], of[4 * j4 + 3]};
    *reinterpret_cast<f32x4*>(op + 4 * j4) = o;
  }
}

extern "C" void kernel_launch(void* const* d_in, const int* in_sizes, int n_in,
                              void* d_out, int out_size, void* d_ws,
                              size_t ws_size, hipStream_t stream) {
  const float* x  = (const float*)d_in[0];
  const float* Wq = (const float*)d_in[1];
  const float* bq = (const float*)d_in[2];
  const float* Wk = (const float*)d_in[3];
  const float* bk = (const float*)d_in[4];
  const float* Wv = (const float*)d_in[5];
  const float* bv = (const float*)d_in[6];

  char* ws = (char*)d_ws;
  bf16* xb  = (bf16*)ws;                          // 16 MB: x as bf16
  bf16* Wt  = (bf16*)(ws + (size_t)16777216);     // 6 MB: 3x W^T bf16
  bf16* QKV = (bf16*)(ws + (size_t)23068672);     // 48 MB: Q,K,V bf16
  float* outf = (float*)d_out;

  // 1) cast x -> bf16 (8192*1024 elems, 4/thread)
  cast_bf16_kernel<<<8192, 256, 0, stream>>>(x, xb, 8192 * 1024 / 4);
  // 2) transpose+cast the three weights
  transpose_cast_kernel<<<dim3(32, 32, 3), 256, 0, stream>>>(Wq, Wk, Wv, Wt);
  // 3) QKV projection GEMMs (z = q/k/v)
  qkv_gemm_kernel<<<dim3(8, 64, 3), 256, 0, stream>>>(xb, Wt, bq, bk, bv, QKV);
  // 4) windowed attention
  local_attn_kernel<<<2048, 256, 0, stream>>>(QKV, outf);
}

// Round 4
// 102.503 us; speedup vs baseline: 1.1164x; 1.1164x over previous
//
#include <hip/hip_runtime.h>
#include <hip/hip_bf16.h>

typedef __bf16 bf16;
typedef __attribute__((ext_vector_type(4))) __bf16 bf16x4;
typedef __attribute__((ext_vector_type(8))) __bf16 bf16x8;
typedef __attribute__((ext_vector_type(4))) float f32x4;

#define GLD_LDS16(g, l)                                              \
  __builtin_amdgcn_global_load_lds(                                  \
      (const __attribute__((address_space(1))) void*)(g),            \
      (__attribute__((address_space(3))) void*)(l), 16, 0, 0)

// ---------------- cast f32 -> bf16, vectorized ----------------
__global__ void cast_bf16_kernel(const float* __restrict__ in,
                                 bf16* __restrict__ out, int n4) {
  int i = blockIdx.x * blockDim.x + threadIdx.x;
  if (i >= n4) return;
  float4 v = reinterpret_cast<const float4*>(in)[i];
  bf16x4 o;
  o[0] = (bf16)v.x; o[1] = (bf16)v.y; o[2] = (bf16)v.z; o[3] = (bf16)v.w;
  reinterpret_cast<bf16x4*>(out)[i] = o;
}

// ------- transpose + cast W (K,N) -> Wt (N,K) bf16; [3][1024][1024] -------
__global__ void transpose_cast_kernel(const float* __restrict__ Wq,
                                      const float* __restrict__ Wk,
                                      const float* __restrict__ Wv,
                                      bf16* __restrict__ Wt) {
  __shared__ float tile[32][33];
  const int z = blockIdx.z;
  const float* W = (z == 0) ? Wq : ((z == 1) ? Wk : Wv);
  bf16* out = Wt + (size_t)z * 1024 * 1024;
  const int k0 = blockIdx.x * 32, n0 = blockIdx.y * 32;
  const int t = threadIdx.x;
  const int r = t >> 3, c = (t & 7) * 4;
  float4 v = *reinterpret_cast<const float4*>(&W[(size_t)(k0 + r) * 1024 + n0 + c]);
  tile[r][c + 0] = v.x; tile[r][c + 1] = v.y;
  tile[r][c + 2] = v.z; tile[r][c + 3] = v.w;
  __syncthreads();
  bf16x4 o;
  o[0] = (bf16)tile[c + 0][r]; o[1] = (bf16)tile[c + 1][r];
  o[2] = (bf16)tile[c + 2][r]; o[3] = (bf16)tile[c + 3][r];
  *reinterpret_cast<bf16x4*>(&out[(size_t)(n0 + r) * 1024 + k0 + c]) = o;
}

// --------- fused QKV GEMM: C[8192][3072] = x @ Wt^T + bias ----------------
// BM=256 BN=128 BK=64, 8 waves (4Mx2N, per-wave 64x64), 3-deep LDS pipeline,
// counted vmcnt(6), XOR-swizzle (row&7)<<4 on LDS (pre-swizzled global src),
// 2 phases/tile x 16 MFMA with setprio.
__global__ __launch_bounds__(512, 2) void qkv_gemm_kernel(
    const bf16* __restrict__ xb, const bf16* __restrict__ Wt,
    const float* __restrict__ bq, const float* __restrict__ bk,
    const float* __restrict__ bv, bf16* __restrict__ QKV) {
  __shared__ bf16 ldsA[3][256 * 64];  // 96 KB (3 x 32 KB)
  __shared__ bf16 ldsB[3][128 * 64];  // 48 KB (3 x 16 KB)

  const int n0g = blockIdx.x * 128;     // global col tile (0..2944)
  const int m0 = blockIdx.y * 256;      // global row tile
  const int z = n0g >> 10;              // which of q/k/v this block is in
  const float* bias = (z == 0) ? bq : ((z == 1) ? bk : bv);
  const int nloc = n0g & 1023;

  const int t = threadIdx.x;
  const int lane = t & 63, wid = t >> 6;
  const int wr = wid >> 1, wc = wid & 1;     // 4M x 2N waves
  const int l15 = lane & 15, kg = lane >> 4;

  // staging geometry: chunk = 64 rows x 64 cols (8 KB), 512 thr x 16 B
  const int trow = t >> 3;                              // 0..63
  const int cdst = (t & 7) * 8;                         // LDS col (elems)
  const int csrc = (((t & 7) * 16) ^ ((trow & 7) << 4)) >> 1;  // swizzled src col

  bf16* const A0 = &ldsA[0][0]; bf16* const A1 = &ldsA[1][0]; bf16* const A2 = &ldsA[2][0];
  bf16* const B0 = &ldsB[0][0]; bf16* const B1 = &ldsB[1][0]; bf16* const B2 = &ldsB[2][0];

  auto stageA = [&](int c, int kt, bf16* Ab) {
    GLD_LDS16(xb + (size_t)(m0 + c * 64 + trow) * 1024 + kt + csrc,
              Ab + (c * 64 + trow) * 64 + cdst);
  };
  auto stageB = [&](int c, int kt, bf16* Bb) {
    GLD_LDS16(Wt + (size_t)(n0g + c * 64 + trow) * 1024 + kt + csrc,
              Bb + (c * 64 + trow) * 64 + cdst);
  };
  // swizzled fragment reads (row&7 == l15&7 since offsets are x16)
  auto readA = [&](const bf16* Ab, int mi, int ks) {
    const int row = wr * 64 + mi * 16 + l15;
    const int colb = (ks * 64 + kg * 16) ^ ((l15 & 7) << 4);
    return *reinterpret_cast<const bf16x8*>(Ab + row * 64 + (colb >> 1));
  };
  auto readB = [&](const bf16* Bb, int ni, int ks) {
    const int row = wc * 64 + ni * 16 + l15;
    const int colb = (ks * 64 + kg * 16) ^ ((l15 & 7) << 4);
    return *reinterpret_cast<const bf16x8*>(Bb + row * 64 + (colb >> 1));
  };

  f32x4 acc[4][4];
#pragma unroll
  for (int i = 0; i < 4; ++i)
#pragma unroll
    for (int j = 0; j < 4; ++j) { f32x4 zz = {0.f, 0.f, 0.f, 0.f}; acc[i][j] = zz; }

  // prologue: stage tile 0 -> buf0, tile 1 -> buf1 (12 loads outstanding)
#pragma unroll
  for (int c = 0; c < 4; ++c) stageA(c, 0, A0);
#pragma unroll
  for (int c = 0; c < 2; ++c) stageB(c, 0, B0);
#pragma unroll
  for (int c = 0; c < 4; ++c) stageA(c, 64, A1);
#pragma unroll
  for (int c = 0; c < 2; ++c) stageB(c, 64, B1);

  bf16 *Ar = A0, *An = A1, *Aw = A2;
  bf16 *Br = B0, *Bn = B1, *Bw = B2;

  for (int tt = 0; tt < 16; ++tt) {
    // boundary: retire tile tt's 6 loads, keep tile tt+1's 6 in flight
    if (tt < 15) asm volatile("s_waitcnt vmcnt(6)" ::: "memory");
    else         asm volatile("s_waitcnt vmcnt(0)" ::: "memory");
    __builtin_amdgcn_s_barrier();
    const int ktgt = (tt + 2) * 64;

    // ---- phase A: read A[mi 0..1] + all B frags; stage 3 chunks of tt+2
    bf16x8 a01[2][2], bfr[4][2];
#pragma unroll
    for (int mi = 0; mi < 2; ++mi)
#pragma unroll
      for (int ks = 0; ks < 2; ++ks) a01[mi][ks] = readA(Ar, mi, ks);
#pragma unroll
    for (int ni = 0; ni < 4; ++ni)
#pragma unroll
      for (int ks = 0; ks < 2; ++ks) bfr[ni][ks] = readB(Br, ni, ks);
    if (tt < 14) { stageA(0, ktgt, Aw); stageA(1, ktgt, Aw); stageB(0, ktgt, Bw); }
    __builtin_amdgcn_s_barrier();
    __builtin_amdgcn_s_setprio(1);
#pragma unroll
    for (int mi = 0; mi < 2; ++mi)
#pragma unroll
      for (int ni = 0; ni < 4; ++ni) {
        acc[mi][ni] = __builtin_amdgcn_mfma_f32_16x16x32_bf16(a01[mi][0], bfr[ni][0], acc[mi][ni], 0, 0, 0);
        acc[mi][ni] = __builtin_amdgcn_mfma_f32_16x16x32_bf16(a01[mi][1], bfr[ni][1], acc[mi][ni], 0, 0, 0);
      }
    __builtin_amdgcn_s_setprio(0);

    // ---- phase B: read A[mi 2..3] (B frags live); stage remaining 3 chunks
    bf16x8 a23[2][2];
#pragma unroll
    for (int mi = 0; mi < 2; ++mi)
#pragma unroll
      for (int ks = 0; ks < 2; ++ks) a23[mi][ks] = readA(Ar, mi + 2, ks);
    if (tt < 14) { stageA(2, ktgt, Aw); stageA(3, ktgt, Aw); stageB(1, ktgt, Bw); }
    __builtin_amdgcn_s_barrier();
    __builtin_amdgcn_s_setprio(1);
#pragma unroll
    for (int mi = 0; mi < 2; ++mi)
#pragma unroll
      for (int ni = 0; ni < 4; ++ni) {
        acc[mi + 2][ni] = __builtin_amdgcn_mfma_f32_16x16x32_bf16(a23[mi][0], bfr[ni][0], acc[mi + 2][ni], 0, 0, 0);
        acc[mi + 2][ni] = __builtin_amdgcn_mfma_f32_16x16x32_bf16(a23[mi][1], bfr[ni][1], acc[mi + 2][ni], 0, 0, 0);
      }
    __builtin_amdgcn_s_setprio(0);

    bf16* tA = Ar; Ar = An; An = Aw; Aw = tA;
    bf16* tB = Br; Br = Bn; Bn = Bw; Bw = tB;
  }

  // epilogue: C/D layout col = lane&15, row = (lane>>4)*4 + reg  [m89/m91]
  const int rowb = kg * 4;
#pragma unroll
  for (int ni = 0; ni < 4; ++ni) {
    const int cl = wc * 64 + ni * 16 + l15;
    const float bv_ = bias[nloc + cl];
#pragma unroll
    for (int mi = 0; mi < 4; ++mi) {
      const int row = m0 + wr * 64 + mi * 16 + rowb;
#pragma unroll
      for (int j = 0; j < 4; ++j)
        QKV[(size_t)(row + j) * 3072 + n0g + cl] = (bf16)(acc[mi][ni][j] + bv_);
    }
  }
}

// ------- local attention, window +-2; QKV fused rows [p][3072] ------------
__global__ void local_attn_kernel(const bf16* __restrict__ QKV,
                                  float* __restrict__ out) {
  const int t = threadIdx.x;
  const int lane = t & 63, wid = t >> 6;
  const int p = blockIdx.x * 4 + wid;  // b*2048 + s
  const int s = p & 2047;
  const size_t hoff = (size_t)lane * 16;

  float qf[16];
  {
    const bf16* qp = QKV + (size_t)p * 3072 + hoff;
    bf16x8 q0 = *reinterpret_cast<const bf16x8*>(qp);
    bf16x8 q1 = *reinterpret_cast<const bf16x8*>(qp + 8);
#pragma unroll
    for (int j = 0; j < 8; ++j) { qf[j] = (float)q0[j]; qf[8 + j] = (float)q1[j]; }
  }

  float sc[5];
#pragma unroll
  for (int w = 0; w < 5; ++w) {
    const int sp = s + w - 2;  // wave-uniform
    if (sp < 0 || sp >= 2048) { sc[w] = -__builtin_inff(); continue; }
    const bf16* kp = QKV + (size_t)(p + w - 2) * 3072 + 1024 + hoff;
    bf16x8 k0 = *reinterpret_cast<const bf16x8*>(kp);
    bf16x8 k1 = *reinterpret_cast<const bf16x8*>(kp + 8);
    float d = 0.f;
#pragma unroll
    for (int j = 0; j < 8; ++j) d += qf[j] * (float)k0[j] + qf[8 + j] * (float)k1[j];
#pragma unroll
    for (int off = 32; off >= 1; off >>= 1) d += __shfl_xor(d, off, 64);
    sc[w] = d * (1.0f / 32.0f);  // /sqrt(1024)
  }

  float m = -__builtin_inff();
#pragma unroll
  for (int w = 0; w < 5; ++w) m = fmaxf(m, sc[w]);
  float e[5], sum = 0.f;
#pragma unroll
  for (int w = 0; w < 5; ++w) { e[w] = __expf(sc[w] - m); sum += e[w]; }
  const float inv = 1.0f / sum;

  float of[16];
#pragma unroll
  for (int j = 0; j < 16; ++j) of[j] = 0.f;
#pragma unroll
  for (int w = 0; w < 5; ++w) {
    const int sp = s + w - 2;
    if (sp < 0 || sp >= 2048) continue;
    const float pw = e[w] * inv;
    const bf16* vp = QKV + (size_t)(p + w - 2) * 3072 + 2048 + hoff;
    bf16x8 v0 = *reinterpret_cast<const bf16x8*>(vp);
    bf16x8 v1 = *reinterpret_cast<const bf16x8*>(vp + 8);
#pragma unroll
    for (int j = 0; j < 8; ++j) { of[j] += pw * (float)v0[j]; of[8 + j] += pw * (float)v1[j]; }
  }

  float* op = out + (size_t)p * 1024 + hoff;
#pragma unroll
  for (int j4 = 0; j4 < 4; ++j4) {
    f32x4 o = {of[4 * j4 + 0], of[4 * j4 + 1], of[4 * j4 + 2], of[4 * j4 + 3]};
    *reinterpret_cast<f32x4*>(op + 4 * j4) = o;
  }
}

extern "C" void kernel_launch(void* const* d_in, const int* in_sizes, int n_in,
                              void* d_out, int out_size, void* d_ws,
                              size_t ws_size, hipStream_t stream) {
  const float* x  = (const float*)d_in[0];
  const float* Wq = (const float*)d_in[1];
  const float* bq = (const float*)d_in[2];
  const float* Wk = (const float*)d_in[3];
  const float* bk = (const float*)d_in[4];
  const float* Wv = (const float*)d_in[5];
  const float* bv = (const float*)d_in[6];

  char* ws = (char*)d_ws;
  bf16* xb  = (bf16*)ws;                       // 16 MB: x as bf16
  bf16* Wt  = (bf16*)(ws + (size_t)16777216);  // 6 MB: [3072][1024] W^T bf16
  bf16* QKV = (bf16*)(ws + (size_t)23068672);  // 48 MB: fused [8192][3072]
  float* outf = (float*)d_out;

  cast_bf16_kernel<<<8192, 256, 0, stream>>>(x, xb, 8192 * 1024 / 4);
  transpose_cast_kernel<<<dim3(32, 32, 3), 256, 0, stream>>>(Wq, Wk, Wv, Wt);
  qkv_gemm_kernel<<<dim3(24, 32), 512, 0, stream>>>(xb, Wt, bq, bk, bv, QKV);
  local_attn_kernel<<<2048, 256, 0, stream>>>(QKV, outf);
}